// Round 17
// baseline (350.722 us; speedup 1.0000x reference)
//
#include <hip/hip_runtime.h>

// B=32, N=36, D=2048, C=4, H=512.
// Out[b,i,d] = max_j [ sum_k Wfout[k,d]*(fl[i,k]*fr[j,k])
//                    + sum_ab Mc[ab,d]*(coords[i,a]*coords[j,b]) ] + mm[b,i,d]
// v3: coord branch collapsed via Mc[ab,d]; K: 1024 -> 544 = 17 kc-chunks.
// v5: XCD-clustered grid map + k_mc folded into k_prep.
// v9: counted-vmcnt ring (k_pairwise 121us).
// v10: k_prod deleted, products fused in-loop — SPILLED (bb[9] 36 VGPR +
//      staging > 128-reg cap; WRITE 9->133MB).
// v11: v10 minus bb[9] — B-fragments read PER-T transiently (4 VGPR) inside
//      the MFMA loop; steady-state live set ~52 VGPR + 72 AGPR <= 128.
//      Spill gate: WRITE_SIZE must stay ~9 MB.
// v11.3: identical resubmit (rounds 14-16 were infra failures; this kernel
//        has never actually run on hardware).

typedef __attribute__((ext_vector_type(8))) short short8;
typedef __attribute__((ext_vector_type(4))) short short4v;
typedef __attribute__((ext_vector_type(4))) float f32x4;

__device__ __forceinline__ float bf2f(unsigned short h) {
  return __uint_as_float(((unsigned int)h) << 16);
}
__device__ __forceinline__ unsigned short f2bf(float f) {
  unsigned int u = __float_as_uint(f);
  u += 0x7FFFu + ((u >> 16) & 1u);
  return (unsigned short)(u >> 16);
}

// 8 bf16 products -> bf16 (identical numerics to old k_prod)
__device__ __forceinline__ short8 prod8(short8 cl, short8 cr) {
  short8 p;
#pragma unroll
  for (int e = 0; e < 8; ++e)
    p[e] = (short)f2bf(bf2f((unsigned short)cl[e]) * bf2f((unsigned short)cr[e]));
  return p;
}

// ---------------------------------------------------------------------------
// K_prep: bid<2304: mm -> bf16 (mmb).
//         bid>=2304: weights -> MFMA fragment order:
//           WS  (A for k_pairwise): kc<16 from Wfout[k,d] (k=kc*32+q*8+e),
//                kc==16: Mc[kk,d] = sum_h Wcl[a,h]Wcr[b,h]Wcout[h,d] computed
//                inline (kk=qv*8+e<16, a=kk>>2, b=kk&3; qv>=2 -> 0 pad)
//           WS2 (B for k_proj_feat): (Wfl|Wfr)^T fragments.
__global__ __launch_bounds__(256) void k_prep(
    const float* __restrict__ mm, const float* __restrict__ Wfout,
    const float* __restrict__ Wcl, const float* __restrict__ Wcr,
    const float* __restrict__ Wcout, const float* __restrict__ Wfl,
    const float* __restrict__ Wfr, unsigned short* __restrict__ mmb,
    unsigned short* __restrict__ WS, unsigned short* __restrict__ WS2) {
  const int bid = blockIdx.x;
  if (bid < 2304) {
    int idx = bid * 256 + threadIdx.x;  // 0 .. 1152*512-1
    int row = idx >> 9, h = idx & 511;
    float4 m4 = *(const float4*)(mm + (size_t)row * 2048 + h * 4);
    short4v o;
    o[0] = (short)f2bf(m4.x); o[1] = (short)f2bf(m4.y);
    o[2] = (short)f2bf(m4.z); o[3] = (short)f2bf(m4.w);
    *(short4v*)(mmb + (size_t)row * 2048 + h * 4) = o;
  } else {
    int gi = (bid - 2304) * 256 + threadIdx.x;  // 0..401407
    if (gi < 139264) {
      // WS granule gi = ((g2*17+kc)*4+q)*16+n ; elem e: d=g2*16+n, k=kc*32+q*8+e
      int n = gi & 15, qv = (gi >> 4) & 3, rest = gi >> 6;
      int kc = rest % 17, g2 = rest / 17;
      int d = g2 * 16 + n;
      short8 o;
      if (kc < 16) {
        int kbase = kc * 32 + qv * 8;
        const float* src = Wfout + (size_t)kbase * 2048 + d;
#pragma unroll
        for (int e = 0; e < 8; ++e) o[e] = (short)f2bf(src[(size_t)e * 2048]);
      } else if (qv < 2) {
        // inline Mc: o[e] = sum_h Wcl[qv*2+(e>>2),h]*Wcr[e&3,h]*Wcout[h,d]
        float acc[8];
#pragma unroll
        for (int e = 0; e < 8; ++e) acc[e] = 0.f;
#pragma unroll 4
        for (int h = 0; h < 512; ++h) {
          float wo = Wcout[(size_t)h * 2048 + d];
          float c0 = Wcl[(qv * 2 + 0) * 512 + h] * wo;
          float c1 = Wcl[(qv * 2 + 1) * 512 + h] * wo;
          float r0 = Wcr[h], r1 = Wcr[512 + h];
          float r2 = Wcr[1024 + h], r3 = Wcr[1536 + h];
          acc[0] += c0 * r0; acc[1] += c0 * r1;
          acc[2] += c0 * r2; acc[3] += c0 * r3;
          acc[4] += c1 * r0; acc[5] += c1 * r1;
          acc[6] += c1 * r2; acc[7] += c1 * r3;
        }
#pragma unroll
        for (int e = 0; e < 8; ++e) o[e] = (short)f2bf(acc[e]);
      } else {
#pragma unroll
        for (int e = 0; e < 8; ++e) o[e] = 0;
      }
      *(short8*)(WS + (size_t)gi * 8) = o;
    } else {
      // WS2 granule gj = ((cg*64+kc)*4+q)*16+n ; elem e: col=cg*16+n, dd=kc*32+q*8+e
      int gj = gi - 139264;
      int n = gj & 15, qv = (gj >> 4) & 3, kc = (gj >> 6) & 63, cg = gj >> 12;
      int col = cg * 16 + n;
      int dbase = kc * 32 + qv * 8;
      const float* src = (col < 512) ? (Wfl + (size_t)dbase * 512 + col)
                                     : (Wfr + (size_t)dbase * 512 + (col - 512));
      short8 o;
#pragma unroll
      for (int e = 0; e < 8; ++e) o[e] = (short)f2bf(src[(size_t)e * 512]);
      *(short8*)(WS2 + (size_t)gj * 8) = o;
    }
  }
}

// ---------------------------------------------------------------------------
// K3: feature projection O[row,col] = sum_dd mmb[row,dd]*Wlr[dd,col]
//  col<512 -> Fl[row][col] ; else -> Fr[row][col-512]   (bf16 out)
__global__ __launch_bounds__(256) void k_proj_feat(
    const unsigned short* __restrict__ mmb, const unsigned short* __restrict__ WS2,
    unsigned short* __restrict__ Fl, unsigned short* __restrict__ Fr) {
  const int tid = threadIdx.x;
  const int lane = tid & 63, w = tid >> 6;
  const int n = lane & 15, q = lane >> 4;
  const int m0 = blockIdx.y * 16;
  const int cg = blockIdx.x * 4 + w;  // 0..63
  const int c0 = cg * 16;

  f32x4 acc = {0.f, 0.f, 0.f, 0.f};
#pragma unroll 4
  for (int kc = 0; kc < 64; ++kc) {
    short8 a = *(const short8*)(mmb + (size_t)(m0 + n) * 2048 + kc * 32 + q * 8);
    short8 b = *(const short8*)(WS2 + (size_t)(cg * 64 + kc) * 512 + lane * 8);
    acc = __builtin_amdgcn_mfma_f32_16x16x32_bf16(a, b, acc, 0, 0, 0);
  }
#pragma unroll
  for (int e = 0; e < 4; ++e) {
    int row = m0 + q * 4 + e;
    int col = c0 + n;
    unsigned short v = f2bf(acc[e]);
    if (col < 512) Fl[(size_t)row * 512 + col] = v;
    else           Fr[(size_t)row * 512 + (col - 512)] = v;
  }
}

// ---------------------------------------------------------------------------
// K4 (fused): streaming GEMM + in-loop pair products + max-over-j + residual.
// 512 thr / 8 waves, r=2, XCD-clustered grid (v5 map). NK=17 chunks.
// LDS: ring[2][8*512] dbuf (granules t=0..7) + g8[16*512] (granule 8, all
// feature chunks; prologue) + c16[9*512] (coord chunk 16; prologue) = 41 KB.
// Body c (0..14): issue cl/cr(c+1) + A(c+1); MFMA(c) with PER-T TRANSIENT
// B reads (v11: no bb[9] array -> live set fits 128-reg cap); products(c+1)
// -> ring[(c+1)&1]; __syncthreads. Then chunk 15 (ring[1]), chunk 16 (c16).
// Granule t=w: g=g0+(w>>1), j=(w&1)*16+n, k=kc*32+q*8+e (old k_prod layout).
__global__ __launch_bounds__(512, 4) void k_pairwise(
    const unsigned short* __restrict__ Fl, const unsigned short* __restrict__ Fr,
    const float* __restrict__ coords, const unsigned short* __restrict__ WS,
    const float* __restrict__ mm, float* __restrict__ out) {
  __shared__ __align__(16) unsigned short ring[2][8 * 512];  // 16 KB
  __shared__ __align__(16) unsigned short g8[16 * 512];      // 16 KB
  __shared__ __align__(16) unsigned short c16[9 * 512];      // 9 KB

  const int tid = threadIdx.x;
  const int lane = tid & 63, w = tid >> 6;  // w 0..7
  const int n = lane & 15, q = lane >> 4;
  const int bx = blockIdx.x;
  const int x = bx & 7;       // XCD id under round-robin dispatch
  const int m = bx >> 3;      // 0..287 per-XCD slot
  const int dt = m & 7;       // d-tile: siblings consecutive on the XCD
  const int qg = x * 36 + (m >> 3);  // qg clustered per XCD (bijective)
  const int g0 = qg * 4;
  const int b36 = (qg / 9) * 36;

  f32x4 acc[9][2];
#pragma unroll
  for (int t = 0; t < 9; ++t)
#pragma unroll
    for (int r = 0; r < 2; ++r) acc[t][r] = (f32x4){0.f, 0.f, 0.f, 0.f};

  // A granule (r, kc): WS + ((dt*16 + w*2 + r)*17 + kc)*512 + lane*8
  const unsigned short* Abase = WS + ((size_t)(dt * 16 + w * 2) * 17) * 512 + lane * 8;

  // primary product slot (granule t=w): g=g0+(w>>1), j=(w&1)*16+n
  const int gp = g0 + (w >> 1);
  const int jp = (w & 1) * 16 + n;
  const unsigned short* FlP = Fl + (size_t)gp * 512 + q * 8;         // +kc*32
  const unsigned short* FrP = Fr + (size_t)(b36 + jp) * 512 + q * 8; // +kc*32
  // shared-granule slot (t=8): g=g0+(n>>2), j=32+(n&3)
  const int gs = g0 + (n >> 2);
  const int js = 32 + (n & 3);

  short8 aR[2], aN[2];

  // ---- prologue ----
  // chunk 0 products -> ring[0]
  {
    short8 cl = *(const short8*)(FlP);
    short8 cr = *(const short8*)(FrP);
    *(short8*)(&ring[0][w * 512 + lane * 8]) = prod8(cl, cr);
  }
  // g8: granule t=8 for feature chunks s=w and s=w+8
#pragma unroll
  for (int si = 0; si < 2; ++si) {
    int s = w + si * 8;
    short8 cl = *(const short8*)(Fl + (size_t)gs * 512 + s * 32 + q * 8);
    short8 cr = *(const short8*)(Fr + (size_t)(b36 + js) * 512 + s * 32 + q * 8);
    *(short8*)(&g8[s * 512 + lane * 8]) = prod8(cl, cr);
  }
  // c16: coord-chunk granules. t=w uses (gp,jp); wave 0 also does t=8 (gs,js).
  {
    short8 cp;
    if (q < 2) {
      float4 ci = *(const float4*)(coords + (size_t)gp * 4);
      float4 cj = *(const float4*)(coords + (size_t)(b36 + jp) * 4);
#pragma unroll
      for (int e = 0; e < 8; ++e) {
        int a = q * 2 + (e >> 2);
        float ca = (a == 0) ? ci.x : (a == 1) ? ci.y : (a == 2) ? ci.z : ci.w;
        float cb = ((e & 3) == 0) ? cj.x : ((e & 3) == 1) ? cj.y
                 : ((e & 3) == 2) ? cj.z : cj.w;
        cp[e] = (short)f2bf(ca * cb);
      }
    } else {
#pragma unroll
      for (int e = 0; e < 8; ++e) cp[e] = 0;
    }
    *(short8*)(&c16[w * 512 + lane * 8]) = cp;
    if (w == 0) {
      short8 cs;
      if (q < 2) {
        float4 ci = *(const float4*)(coords + (size_t)gs * 4);
        float4 cj = *(const float4*)(coords + (size_t)(b36 + js) * 4);
#pragma unroll
        for (int e = 0; e < 8; ++e) {
          int a = q * 2 + (e >> 2);
          float ca = (a == 0) ? ci.x : (a == 1) ? ci.y : (a == 2) ? ci.z : ci.w;
          float cb = ((e & 3) == 0) ? cj.x : ((e & 3) == 1) ? cj.y
                   : ((e & 3) == 2) ? cj.z : cj.w;
          cs[e] = (short)f2bf(ca * cb);
        }
      } else {
#pragma unroll
        for (int e = 0; e < 8; ++e) cs[e] = 0;
      }
      *(short8*)(&c16[8 * 512 + lane * 8]) = cs;
    }
  }
  aR[0] = *(const short8*)(Abase);
  aR[1] = *(const short8*)(Abase + 17 * 512);
  __syncthreads();

  // ---- main loop: chunks 0..14, staging products for c+1 ----
#pragma unroll 2
  for (int c = 0; c < 15; ++c) {
    const int buf = c & 1;
    // issue-early: product operands for chunk c+1 + A(c+1)
    short8 cl = *(const short8*)(FlP + (c + 1) * 32);
    short8 cr = *(const short8*)(FrP + (c + 1) * 32);
    aN[0] = *(const short8*)(Abase + (size_t)(c + 1) * 512);
    aN[1] = *(const short8*)(Abase + (size_t)(17 + c + 1) * 512);

    // MFMA phase: chunk c — per-t transient B reads (no bb[] array)
#pragma unroll
    for (int t = 0; t < 8; ++t) {
      short8 bt = *(const short8*)(&ring[buf][t * 512 + lane * 8]);
      acc[t][0] = __builtin_amdgcn_mfma_f32_16x16x32_bf16(aR[0], bt, acc[t][0], 0, 0, 0);
      acc[t][1] = __builtin_amdgcn_mfma_f32_16x16x32_bf16(aR[1], bt, acc[t][1], 0, 0, 0);
    }
    {
      short8 b8 = *(const short8*)(&g8[c * 512 + lane * 8]);
      acc[8][0] = __builtin_amdgcn_mfma_f32_16x16x32_bf16(aR[0], b8, acc[8][0], 0, 0, 0);
      acc[8][1] = __builtin_amdgcn_mfma_f32_16x16x32_bf16(aR[1], b8, acc[8][1], 0, 0, 0);
    }
    // consume-late: products for chunk c+1 into the other buffer
    *(short8*)(&ring[buf ^ 1][w * 512 + lane * 8]) = prod8(cl, cr);
    __syncthreads();
    aR[0] = aN[0];
    aR[1] = aN[1];
  }

  // chunk 15 (ring[1], g8[15]); load A(16); no staging, no barrier after
  {
    aN[0] = *(const short8*)(Abase + (size_t)16 * 512);
    aN[1] = *(const short8*)(Abase + (size_t)(17 + 16) * 512);
#pragma unroll
    for (int t = 0; t < 8; ++t) {
      short8 bt = *(const short8*)(&ring[1][t * 512 + lane * 8]);
      acc[t][0] = __builtin_amdgcn_mfma_f32_16x16x32_bf16(aR[0], bt, acc[t][0], 0, 0, 0);
      acc[t][1] = __builtin_amdgcn_mfma_f32_16x16x32_bf16(aR[1], bt, acc[t][1], 0, 0, 0);
    }
    {
      short8 b8 = *(const short8*)(&g8[15 * 512 + lane * 8]);
      acc[8][0] = __builtin_amdgcn_mfma_f32_16x16x32_bf16(aR[0], b8, acc[8][0], 0, 0, 0);
      acc[8][1] = __builtin_amdgcn_mfma_f32_16x16x32_bf16(aR[1], b8, acc[8][1], 0, 0, 0);
    }
  }
  // chunk 16 (coord, c16 static)
  {
#pragma unroll
    for (int t = 0; t < 9; ++t) {
      short8 bt = *(const short8*)(&c16[t * 512 + lane * 8]);
      acc[t][0] = __builtin_amdgcn_mfma_f32_16x16x32_bf16(aN[0], bt, acc[t][0], 0, 0, 0);
      acc[t][1] = __builtin_amdgcn_mfma_f32_16x16x32_bf16(aN[1], bt, acc[t][1], 0, 0, 0);
    }
  }

  // epilogue: per (ii,r,e): max over full tiles 2ii,2ii+1 (j=n, 16+n) and the
  // shared tile's lanes with n>>2==ii (j=32+(n&3)); xor-reduce over 16 n-lanes.
#pragma unroll
  for (int r = 0; r < 2; ++r) {
#pragma unroll
    for (int e = 0; e < 4; ++e) {
      float vs = acc[8][r][e];
#pragma unroll
      for (int ii = 0; ii < 4; ++ii) {
        float v = fmaxf(acc[ii * 2][r][e], acc[ii * 2 + 1][r][e]);
        v = fmaxf(v, ((n >> 2) == ii) ? vs : -1e30f);
#pragma unroll
        for (int s = 1; s < 16; s <<= 1) v = fmaxf(v, __shfl_xor(v, s, 64));
        if (n == 0) {
          int d = dt * 256 + w * 32 + r * 16 + q * 4 + e;
          size_t o = (size_t)(g0 + ii) * 2048 + d;
          out[o] = v + mm[o];
        }
      }
    }
  }
}

// ---------------------------------------------------------------------------
extern "C" void kernel_launch(void* const* d_in, const int* in_sizes, int n_in,
                              void* d_out, int out_size, void* d_ws, size_t ws_size,
                              hipStream_t stream) {
  const float* mm     = (const float*)d_in[0];
  const float* coords = (const float*)d_in[1];
  const float* Wcl    = (const float*)d_in[2];
  const float* Wcr    = (const float*)d_in[3];
  const float* Wcout  = (const float*)d_in[4];
  const float* Wfl    = (const float*)d_in[5];
  const float* Wfr    = (const float*)d_in[6];
  const float* Wfout  = (const float*)d_in[7];
  float* out = (float*)d_out;

  // workspace ~14 MB (Pf eliminated)
  unsigned short* Fl  = (unsigned short*)d_ws;              // [1152][512] bf16
  unsigned short* Fr  = Fl + (size_t)1152 * 512;            // [1152][512] bf16
  unsigned short* WS  = Fr + (size_t)1152 * 512;            // 139264 gran x 8
  unsigned short* WS2 = WS + (size_t)139264 * 8;            // 262144 gran x 8
  unsigned short* mmb = WS2 + (size_t)262144 * 8;           // [1152][2048] bf16

  k_prep<<<2304 + 1568, 256, 0, stream>>>(mm, Wfout, Wcl, Wcr, Wcout,
                                          Wfl, Wfr, mmb, WS, WS2);
  k_proj_feat<<<dim3(16, 72), 256, 0, stream>>>(mmb, WS2, Fl, Fr);
  k_pairwise<<<2304, 512, 0, stream>>>(Fl, Fr, coords, WS, mm, out);
}

// Round 18
// 296.704 us; speedup vs baseline: 1.1821x; 1.1821x over previous
//
#include <hip/hip_runtime.h>

// B=32, N=36, D=2048, C=4, H=512.
// Out[b,i,d] = max_j [ sum_k Wfout[k,d]*(fl[i,k]*fr[j,k])
//                    + sum_ab Mc[ab,d]*(coords[i,a]*coords[j,b]) ] + mm[b,i,d]
// v3: coord branch collapsed via Mc[ab,d]; K: 1024 -> 544 = 17 kc-chunks.
// v5: XCD-clustered grid map + k_mc folded into k_prep.
// v9: counted-vmcnt FIFO ring (k_pairwise 121us, WRITE 9.3MB — clean).
// v10/v11: product fusion — SPILLED both times (any in-loop state beyond
//          the v9 live set exceeds the 128-reg envelope). Line abandoned.
// v12: REVERT to exact v9 configuration (k_prod rematerialized), keeping
//      the unroll-4 Mc loop in k_prep from v10/v11.

typedef __attribute__((ext_vector_type(8))) short short8;
typedef __attribute__((ext_vector_type(4))) short short4v;
typedef __attribute__((ext_vector_type(4))) float f32x4;

__device__ __forceinline__ float bf2f(unsigned short h) {
  return __uint_as_float(((unsigned int)h) << 16);
}
__device__ __forceinline__ unsigned short f2bf(float f) {
  unsigned int u = __float_as_uint(f);
  u += 0x7FFFu + ((u >> 16) & 1u);
  return (unsigned short)(u >> 16);
}
// async global->LDS, 16B per lane; lds dest is wave-uniform base + lane*16
__device__ __forceinline__ void gl2lds16(const void* g, void* l) {
  __builtin_amdgcn_global_load_lds(
      (const __attribute__((address_space(1))) unsigned int*)g,
      (__attribute__((address_space(3))) unsigned int*)l, 16, 0, 0);
}

// ---------------------------------------------------------------------------
// K_prep: bid<2304: mm -> bf16 (mmb).
//         bid>=2304: weights -> MFMA fragment order:
//           WS  (A for k_pairwise): kc<16 from Wfout[k,d] (k=kc*32+q*8+e),
//                kc==16: Mc[kk,d] = sum_h Wcl[a,h]Wcr[b,h]Wcout[h,d] computed
//                inline (kk=qv*8+e<16, a=kk>>2, b=kk&3; qv>=2 -> 0 pad)
//           WS2 (B for k_proj_feat): (Wfl|Wfr)^T fragments.
__global__ __launch_bounds__(256) void k_prep(
    const float* __restrict__ mm, const float* __restrict__ Wfout,
    const float* __restrict__ Wcl, const float* __restrict__ Wcr,
    const float* __restrict__ Wcout, const float* __restrict__ Wfl,
    const float* __restrict__ Wfr, unsigned short* __restrict__ mmb,
    unsigned short* __restrict__ WS, unsigned short* __restrict__ WS2) {
  const int bid = blockIdx.x;
  if (bid < 2304) {
    int idx = bid * 256 + threadIdx.x;  // 0 .. 1152*512-1
    int row = idx >> 9, h = idx & 511;
    float4 m4 = *(const float4*)(mm + (size_t)row * 2048 + h * 4);
    short4v o;
    o[0] = (short)f2bf(m4.x); o[1] = (short)f2bf(m4.y);
    o[2] = (short)f2bf(m4.z); o[3] = (short)f2bf(m4.w);
    *(short4v*)(mmb + (size_t)row * 2048 + h * 4) = o;
  } else {
    int gi = (bid - 2304) * 256 + threadIdx.x;  // 0..401407
    if (gi < 139264) {
      // WS granule gi = ((g2*17+kc)*4+q)*16+n ; elem e: d=g2*16+n, k=kc*32+q*8+e
      int n = gi & 15, qv = (gi >> 4) & 3, rest = gi >> 6;
      int kc = rest % 17, g2 = rest / 17;
      int d = g2 * 16 + n;
      short8 o;
      if (kc < 16) {
        int kbase = kc * 32 + qv * 8;
        const float* src = Wfout + (size_t)kbase * 2048 + d;
#pragma unroll
        for (int e = 0; e < 8; ++e) o[e] = (short)f2bf(src[(size_t)e * 2048]);
      } else if (qv < 2) {
        // inline Mc: o[e] = sum_h Wcl[qv*2+(e>>2),h]*Wcr[e&3,h]*Wcout[h,d]
        float acc[8];
#pragma unroll
        for (int e = 0; e < 8; ++e) acc[e] = 0.f;
#pragma unroll 4
        for (int h = 0; h < 512; ++h) {
          float wo = Wcout[(size_t)h * 2048 + d];
          float c0 = Wcl[(qv * 2 + 0) * 512 + h] * wo;
          float c1 = Wcl[(qv * 2 + 1) * 512 + h] * wo;
          float r0 = Wcr[h], r1 = Wcr[512 + h];
          float r2 = Wcr[1024 + h], r3 = Wcr[1536 + h];
          acc[0] += c0 * r0; acc[1] += c0 * r1;
          acc[2] += c0 * r2; acc[3] += c0 * r3;
          acc[4] += c1 * r0; acc[5] += c1 * r1;
          acc[6] += c1 * r2; acc[7] += c1 * r3;
        }
#pragma unroll
        for (int e = 0; e < 8; ++e) o[e] = (short)f2bf(acc[e]);
      } else {
#pragma unroll
        for (int e = 0; e < 8; ++e) o[e] = 0;
      }
      *(short8*)(WS + (size_t)gi * 8) = o;
    } else {
      // WS2 granule gj = ((cg*64+kc)*4+q)*16+n ; elem e: col=cg*16+n, dd=kc*32+q*8+e
      int gj = gi - 139264;
      int n = gj & 15, qv = (gj >> 4) & 3, kc = (gj >> 6) & 63, cg = gj >> 12;
      int col = cg * 16 + n;
      int dbase = kc * 32 + qv * 8;
      const float* src = (col < 512) ? (Wfl + (size_t)dbase * 512 + col)
                                     : (Wfr + (size_t)dbase * 512 + (col - 512));
      short8 o;
#pragma unroll
      for (int e = 0; e < 8; ++e) o[e] = (short)f2bf(src[(size_t)e * 512]);
      *(short8*)(WS2 + (size_t)gj * 8) = o;
    }
  }
}

// ---------------------------------------------------------------------------
// K3: feature projection O[row,col] = sum_dd mmb[row,dd]*Wlr[dd,col]
//  col<512 -> Fl[row][col] ; else -> Fr[row][col-512]   (bf16 out)
__global__ __launch_bounds__(256) void k_proj_feat(
    const unsigned short* __restrict__ mmb, const unsigned short* __restrict__ WS2,
    unsigned short* __restrict__ Fl, unsigned short* __restrict__ Fr) {
  const int tid = threadIdx.x;
  const int lane = tid & 63, w = tid >> 6;
  const int n = lane & 15, q = lane >> 4;
  const int m0 = blockIdx.y * 16;
  const int cg = blockIdx.x * 4 + w;  // 0..63
  const int c0 = cg * 16;

  f32x4 acc = {0.f, 0.f, 0.f, 0.f};
#pragma unroll 4
  for (int kc = 0; kc < 64; ++kc) {
    short8 a = *(const short8*)(mmb + (size_t)(m0 + n) * 2048 + kc * 32 + q * 8);
    short8 b = *(const short8*)(WS2 + (size_t)(cg * 64 + kc) * 512 + lane * 8);
    acc = __builtin_amdgcn_mfma_f32_16x16x32_bf16(a, b, acc, 0, 0, 0);
  }
#pragma unroll
  for (int e = 0; e < 4; ++e) {
    int row = m0 + q * 4 + e;
    int col = c0 + n;
    unsigned short v = f2bf(acc[e]);
    if (col < 512) Fl[(size_t)row * 512 + col] = v;
    else           Fr[(size_t)row * 512 + (col - 512)] = v;
  }
}

// ---------------------------------------------------------------------------
// K_prod: materialize pair "products" in MFMA B-fragment order, quad-packed.
// Granule id = (qg*17 + kc)*9 + t ; lane (q,n), elem e: k = kc*32 + q*8 + e.
//   t<8 : group g = qg*4 + (t>>1), col j = (t&1)*16 + n      (full tiles)
//   t=8 : group g = qg*4 + (n>>2), col j = 32 + (n&3)        (shared remainder)
// kc<16 : P = Fl[g,k] * Fr[b*36+j,k]                (feature products)
// kc==16: P = coords[g,a]*coords[b*36+j,bb], ab=q*8+e (<16), else 0
__global__ __launch_bounds__(256) void k_prod(
    const unsigned short* __restrict__ Fl, const unsigned short* __restrict__ Fr,
    const float* __restrict__ coords, unsigned short* __restrict__ Pf) {
  int idx = blockIdx.x * 256 + threadIdx.x;  // 0 .. 2,820,095
  int lane = idx & 63;
  int gran = idx >> 6;          // 0 .. 44063
  int qg = gran / 153;          // 153 = 17 kc * 9 t granules per quad-group
  int rem = gran - qg * 153;
  int kc = rem / 9;
  int t = rem - kc * 9;
  int n = lane & 15, q = lane >> 4;
  int b = qg / 9;
  int g, j;
  if (t < 8) { g = qg * 4 + (t >> 1); j = (t & 1) * 16 + n; }
  else       { g = qg * 4 + (n >> 2); j = 32 + (n & 3); }
  int rowj = b * 36 + j;
  short8 p;
  if (kc < 16) {
    int k0 = kc * 32 + q * 8;
    short8 cl8 = *(const short8*)(Fl + (size_t)g * 512 + k0);
    short8 cr8 = *(const short8*)(Fr + (size_t)rowj * 512 + k0);
#pragma unroll
    for (int e = 0; e < 8; ++e)
      p[e] = (short)f2bf(bf2f((unsigned short)cl8[e]) * bf2f((unsigned short)cr8[e]));
  } else if (q < 2) {
    float4 ci = *(const float4*)(coords + (size_t)g * 4);
    float4 cj = *(const float4*)(coords + (size_t)rowj * 4);
#pragma unroll
    for (int e = 0; e < 8; ++e) {
      int a = q * 2 + (e >> 2);  // 0..3 (q<2)
      float ca = (a == 0) ? ci.x : (a == 1) ? ci.y : (a == 2) ? ci.z : ci.w;
      float cb = ((e & 3) == 0) ? cj.x : ((e & 3) == 1) ? cj.y
               : ((e & 3) == 2) ? cj.z : cj.w;
      p[e] = (short)f2bf(ca * cb);
    }
  } else {
#pragma unroll
    for (int e = 0; e < 8; ++e) p[e] = 0;
  }
  *(short8*)(Pf + (size_t)idx * 8) = p;
}

// ---------------------------------------------------------------------------
// K4: streaming GEMM + max-over-j + residual. NK=17 chunks.
// 512 thr / 8 waves, r=2, XCD-clustered grid (v5). v9 pipeline:
//   ring[3][8*512] (24KB): granules t=0..7, staged 2 chunks ahead, 1 gl2lds
//   per wave per body (uniform). g8[17*512] (17KB): granule t=8 for all
//   chunks, staged once in prologue.
//   Body(c): load A(c+1) -> slot (c+1)%3; gl2lds stage(c+2); 8x{ds_read;
//   2 MFMA} + g8 MFMA pair using slot c%3; s_waitcnt vmcnt(3); s_barrier.
//   FIFO invariant: barrier drains only stage(c+1) (issued one body ago).
// Manual 3x-unroll (5 iters) -> all ring/slot indices compile-time.
__global__ __launch_bounds__(512, 4) void k_pairwise(
    const unsigned short* __restrict__ Pf, const unsigned short* __restrict__ WS,
    const float* __restrict__ mm, float* __restrict__ out) {
  __shared__ __align__(16) unsigned short ring[3][8 * 512];  // 24 KB
  __shared__ __align__(16) unsigned short g8[17 * 512];      // 17 KB

  const int tid = threadIdx.x;
  const int lane = tid & 63, w = tid >> 6;  // w 0..7
  const int n = lane & 15, q = lane >> 4;
  const int bx = blockIdx.x;
  const int x = bx & 7;       // XCD id under round-robin dispatch
  const int m = bx >> 3;      // 0..287 per-XCD slot
  const int dt = m & 7;       // d-tile: siblings consecutive on the XCD
  const int qg = x * 36 + (m >> 3);  // qg clustered per XCD (bijective)
  const int g0 = qg * 4;

  f32x4 acc[9][2];
#pragma unroll
  for (int t = 0; t < 9; ++t)
#pragma unroll
    for (int r = 0; r < 2; ++r) acc[t][r] = (f32x4){0.f, 0.f, 0.f, 0.f};

  // A granule (r, kc): WS + ((dt*16 + w*2 + r)*17 + kc)*512 + lane*8
  const unsigned short* Abase = WS + ((size_t)(dt * 16 + w * 2) * 17) * 512 + lane * 8;
  // B granule (kc, t): Pf + ((qg*17 + kc)*9 + t)*512 + lane*8
  const unsigned short* Bbase = Pf + (size_t)qg * 17 * 9 * 512;

  short8 a00, a01, a10, a11, a20, a21;  // A slots 0,1,2 (rotation static)

  // ---- prologue: ring chunks 0,1 (granule t=w); g8 all 17 chunks; A(0)
  gl2lds16(Bbase + (size_t)w * 512 + lane * 8, &ring[0][w * 512]);
  gl2lds16(Bbase + (size_t)(9 + w) * 512 + lane * 8, &ring[1][w * 512]);
  for (int s = w; s < 17; s += 8)
    gl2lds16(Bbase + (size_t)(s * 9 + 8) * 512 + lane * 8, &g8[s * 512]);
  a00 = *(const short8*)(Abase);
  a01 = *(const short8*)(Abase + 17 * 512);
  __syncthreads();  // one-time full drain

// Body C: uses A slot SU, loads A(C+1) into slot SN, reads ring[RU],
// stages chunk C+2 into ring[RS]; DOSTAGE/VMN per position.
#define KBODY(C, RU, RS, aU0, aU1, aN0, aN1, DOSTAGE, VMN)                   \
  {                                                                          \
    aN0 = *(const short8*)(Abase + (size_t)((C) + 1) * 512);                 \
    aN1 = *(const short8*)(Abase + (size_t)(17 + (C) + 1) * 512);            \
    if (DOSTAGE) {                                                           \
      const unsigned short* bn =                                             \
          Bbase + (size_t)(((C) + 2) * 9) * 512 + lane * 8;                  \
      gl2lds16(bn + (size_t)w * 512, &ring[RS][w * 512]);                    \
    }                                                                        \
    _Pragma("unroll")                                                        \
    for (int t = 0; t < 8; ++t) {                                            \
      short8 bt = *(const short8*)(&ring[RU][t * 512 + lane * 8]);           \
      acc[t][0] = __builtin_amdgcn_mfma_f32_16x16x32_bf16(aU0, bt, acc[t][0], 0, 0, 0); \
      acc[t][1] = __builtin_amdgcn_mfma_f32_16x16x32_bf16(aU1, bt, acc[t][1], 0, 0, 0); \
    }                                                                        \
    {                                                                        \
      short8 b8 = *(const short8*)(&g8[(C) * 512 + lane * 8]);               \
      acc[8][0] = __builtin_amdgcn_mfma_f32_16x16x32_bf16(aU0, b8, acc[8][0], 0, 0, 0); \
      acc[8][1] = __builtin_amdgcn_mfma_f32_16x16x32_bf16(aU1, b8, acc[8][1], 0, 0, 0); \
    }                                                                        \
    asm volatile("s_waitcnt vmcnt(" #VMN ")" ::: "memory");                  \
    __builtin_amdgcn_s_barrier();                                            \
  }

  // main loop: chunks 0..14 (5 x 3 bodies; ring & A-slot rotation static)
  for (int k3 = 0; k3 < 15; k3 += 3) {
    KBODY(k3 + 0, 0, 2, a00, a01, a10, a11, 1, 3);
    KBODY(k3 + 1, 1, 0, a10, a11, a20, a21, 1, 3);
    KBODY(k3 + 2, 2, 1, a20, a21, a00, a01, 1, 3);
  }
  // chunk 15: slot0 in use, loads A(16)->slot1, no stage; vmcnt(2) drains
  // stage(16) (issued at body 14).
  KBODY(15, 0, 2, a00, a01, a10, a11, 0, 2);
  // chunk 16: final, no loads/stage/barrier
  {
#pragma unroll
    for (int t = 0; t < 8; ++t) {
      short8 bt = *(const short8*)(&ring[1][t * 512 + lane * 8]);
      acc[t][0] = __builtin_amdgcn_mfma_f32_16x16x32_bf16(a10, bt, acc[t][0], 0, 0, 0);
      acc[t][1] = __builtin_amdgcn_mfma_f32_16x16x32_bf16(a11, bt, acc[t][1], 0, 0, 0);
    }
    {
      short8 b8 = *(const short8*)(&g8[16 * 512 + lane * 8]);
      acc[8][0] = __builtin_amdgcn_mfma_f32_16x16x32_bf16(a10, b8, acc[8][0], 0, 0, 0);
      acc[8][1] = __builtin_amdgcn_mfma_f32_16x16x32_bf16(a11, b8, acc[8][1], 0, 0, 0);
    }
  }
#undef KBODY

  // epilogue: per (ii,r,e): max over full tiles 2ii,2ii+1 (j=n, 16+n) and the
  // shared tile's lanes with n>>2==ii (j=32+(n&3)); xor-reduce over 16 n-lanes.
#pragma unroll
  for (int r = 0; r < 2; ++r) {
#pragma unroll
    for (int e = 0; e < 4; ++e) {
      float vs = acc[8][r][e];
#pragma unroll
      for (int ii = 0; ii < 4; ++ii) {
        float v = fmaxf(acc[ii * 2][r][e], acc[ii * 2 + 1][r][e]);
        v = fmaxf(v, ((n >> 2) == ii) ? vs : -1e30f);
#pragma unroll
        for (int s = 1; s < 16; s <<= 1) v = fmaxf(v, __shfl_xor(v, s, 64));
        if (n == 0) {
          int d = dt * 256 + w * 32 + r * 16 + q * 4 + e;
          size_t o = (size_t)(g0 + ii) * 2048 + d;
          out[o] = v + mm[o];
        }
      }
    }
  }
}

// ---------------------------------------------------------------------------
extern "C" void kernel_launch(void* const* d_in, const int* in_sizes, int n_in,
                              void* d_out, int out_size, void* d_ws, size_t ws_size,
                              hipStream_t stream) {
  const float* mm     = (const float*)d_in[0];
  const float* coords = (const float*)d_in[1];
  const float* Wcl    = (const float*)d_in[2];
  const float* Wcr    = (const float*)d_in[3];
  const float* Wcout  = (const float*)d_in[4];
  const float* Wfl    = (const float*)d_in[5];
  const float* Wfr    = (const float*)d_in[6];
  const float* Wfout  = (const float*)d_in[7];
  float* out = (float*)d_out;

  // workspace ~59 MB
  unsigned short* Fl  = (unsigned short*)d_ws;              // [1152][512] bf16
  unsigned short* Fr  = Fl + (size_t)1152 * 512;            // [1152][512] bf16
  unsigned short* WS  = Fr + (size_t)1152 * 512;            // 139264 gran x 8
  unsigned short* WS2 = WS + (size_t)139264 * 8;            // 262144 gran x 8
  unsigned short* mmb = WS2 + (size_t)262144 * 8;           // [1152][2048] bf16
  unsigned short* Pf  = mmb + (size_t)1152 * 2048;          // 44064 gran x 512 (45MB)

  k_prep<<<2304 + 1568, 256, 0, stream>>>(mm, Wfout, Wcl, Wcr, Wcout,
                                          Wfl, Wfr, mmb, WS, WS2);
  k_proj_feat<<<dim3(16, 72), 256, 0, stream>>>(mmb, WS2, Fl, Fr);
  k_prod<<<11016, 256, 0, stream>>>(Fl, Fr, coords, Pf);
  k_pairwise<<<2304, 512, 0, stream>>>(Pf, WS, mm, out);
}

// Round 19
// 286.785 us; speedup vs baseline: 1.2229x; 1.0346x over previous
//
#include <hip/hip_runtime.h>

// B=32, N=36, D=2048, C=4, H=512.
// Out[b,i,d] = max_j [ sum_k Wfout[k,d]*(fl[i,k]*fr[j,k])
//                    + sum_ab Mc[ab,d]*(coords[i,a]*coords[j,b]) ] + mm[b,i,d]
// v3: coord branch collapsed via Mc[ab,d]; K: 1024 -> 544 = 17 kc-chunks.
// v5: XCD-clustered grid map. v9: counted-vmcnt FIFO ring (k_pairwise 116us).
// v10/v11: product fusion — spilled; abandoned. v12: v9 revert (296.7us).
// v13: middle restructure, k_pairwise/k_prod untouched:
//   (a) k_mc: h-PARALLEL Mc (128 blk x 256 thr, 32-iter partials + LDS tree
//       reduce) writing kc=16 WS granules directly in fragment format —
//       kills the 64-wave x 512-serial-iter tail inside k_prep.
//   (b) mmb deleted: k_proj_feat reads mm f32 directly (same f2bf rounding);
//       k_prep loses its bid<2304 half (grid 3872 -> 1568).

typedef __attribute__((ext_vector_type(8))) short short8;
typedef __attribute__((ext_vector_type(4))) float f32x4;

__device__ __forceinline__ float bf2f(unsigned short h) {
  return __uint_as_float(((unsigned int)h) << 16);
}
__device__ __forceinline__ unsigned short f2bf(float f) {
  unsigned int u = __float_as_uint(f);
  u += 0x7FFFu + ((u >> 16) & 1u);
  return (unsigned short)(u >> 16);
}
// async global->LDS, 16B per lane; lds dest is wave-uniform base + lane*16
__device__ __forceinline__ void gl2lds16(const void* g, void* l) {
  __builtin_amdgcn_global_load_lds(
      (const __attribute__((address_space(1))) unsigned int*)g,
      (__attribute__((address_space(3))) unsigned int*)l, 16, 0, 0);
}

// ---------------------------------------------------------------------------
// K_mc: Mc[ab][d] = sum_h Wcl[a,h]Wcr[b,h]Wcout[h,d], written DIRECTLY as the
// kc=16 WS granules (fragment format): granule (g2,16,qv), lane n, elem e
// holds Mc[qv*8+e][g2*16+n] (qv<2), zeros for qv=2,3.
// Block g2 (128 blocks): thread (hs=tid>>4, dl=tid&15): partial acc[16 ab]
// over h in [hs*32, hs*32+32); LDS tree-reduce over 16 hs; write.
__global__ __launch_bounds__(256) void k_mc(
    const float* __restrict__ Wcl, const float* __restrict__ Wcr,
    const float* __restrict__ Wcout, unsigned short* __restrict__ WS) {
  __shared__ float red[16 * 16 * 17];  // [hs][dl] x [ab padded 17] -> no conflicts
  const int tid = threadIdx.x;
  const int dl = tid & 15, hs = tid >> 4;
  const int g2 = blockIdx.x;  // 0..127
  const int d = g2 * 16 + dl;

  float acc[16];
#pragma unroll
  for (int i = 0; i < 16; ++i) acc[i] = 0.f;
#pragma unroll 4
  for (int hh = 0; hh < 32; ++hh) {
    int h = hs * 32 + hh;
    float wo = Wcout[(size_t)h * 2048 + d];
    float c0 = Wcl[h] * wo, c1 = Wcl[512 + h] * wo;
    float c2 = Wcl[1024 + h] * wo, c3 = Wcl[1536 + h] * wo;
    float r0 = Wcr[h], r1 = Wcr[512 + h];
    float r2 = Wcr[1024 + h], r3 = Wcr[1536 + h];
    acc[0] += c0 * r0; acc[1] += c0 * r1; acc[2] += c0 * r2; acc[3] += c0 * r3;
    acc[4] += c1 * r0; acc[5] += c1 * r1; acc[6] += c1 * r2; acc[7] += c1 * r3;
    acc[8] += c2 * r0; acc[9] += c2 * r1; acc[10] += c2 * r2; acc[11] += c2 * r3;
    acc[12] += c3 * r0; acc[13] += c3 * r1; acc[14] += c3 * r2; acc[15] += c3 * r3;
  }
#pragma unroll
  for (int ab = 0; ab < 16; ++ab) red[(hs * 16 + dl) * 17 + ab] = acc[ab];
  __syncthreads();

  // reduce: thread (ab=tid>>4, dl2=tid&15) sums over hs
  const int ab = tid >> 4, dl2 = tid & 15;
  float s = 0.f;
#pragma unroll
  for (int h2 = 0; h2 < 16; ++h2) s += red[(h2 * 16 + dl2) * 17 + ab];
  const int qv = ab >> 3, e = ab & 7;
  const size_t gbase = ((size_t)g2 * 17 + 16) * 4;  // granule base (qv=0)
  WS[((gbase + qv) * 16 + dl2) * 8 + e] = f2bf(s);
  // zero granules qv=2,3: 256 contiguous shorts, one per thread
  WS[(gbase + 2) * 16 * 8 + tid] = 0;
}

// ---------------------------------------------------------------------------
// K_prep: weights -> MFMA fragment order (grid 1568):
//   gi<139264: WS (A for k_pairwise): kc<16 from Wfout[k,d] (k=kc*32+q*8+e);
//              kc==16 granules are owned by k_mc (no-op here).
//   else:      WS2 (B for k_proj_feat): (Wfl|Wfr)^T fragments.
__global__ __launch_bounds__(256) void k_prep(
    const float* __restrict__ Wfout, const float* __restrict__ Wfl,
    const float* __restrict__ Wfr, unsigned short* __restrict__ WS,
    unsigned short* __restrict__ WS2) {
  int gi = blockIdx.x * 256 + threadIdx.x;  // 0..401407
  if (gi < 139264) {
    // WS granule gi = ((g2*17+kc)*4+q)*16+n ; elem e: d=g2*16+n, k=kc*32+q*8+e
    int n = gi & 15, qv = (gi >> 4) & 3, rest = gi >> 6;
    int kc = rest % 17, g2 = rest / 17;
    if (kc < 16) {
      int d = g2 * 16 + n;
      int kbase = kc * 32 + qv * 8;
      const float* src = Wfout + (size_t)kbase * 2048 + d;
      short8 o;
#pragma unroll
      for (int e = 0; e < 8; ++e) o[e] = (short)f2bf(src[(size_t)e * 2048]);
      *(short8*)(WS + (size_t)gi * 8) = o;
    }
    // kc==16: written by k_mc
  } else {
    // WS2 granule gj = ((cg*64+kc)*4+q)*16+n ; elem e: col=cg*16+n, dd=kc*32+q*8+e
    int gj = gi - 139264;
    int n = gj & 15, qv = (gj >> 4) & 3, kc = (gj >> 6) & 63, cg = gj >> 12;
    int col = cg * 16 + n;
    int dbase = kc * 32 + qv * 8;
    const float* src = (col < 512) ? (Wfl + (size_t)dbase * 512 + col)
                                   : (Wfr + (size_t)dbase * 512 + (col - 512));
    short8 o;
#pragma unroll
    for (int e = 0; e < 8; ++e) o[e] = (short)f2bf(src[(size_t)e * 512]);
    *(short8*)(WS2 + (size_t)gj * 8) = o;
  }
}

// ---------------------------------------------------------------------------
// K3: feature projection O[row,col] = sum_dd mm_bf16[row,dd]*Wlr[dd,col]
//  reads mm f32 DIRECTLY (v13: mmb deleted; same f2bf rounding path).
//  col<512 -> Fl[row][col] ; else -> Fr[row][col-512]   (bf16 out)
__global__ __launch_bounds__(256) void k_proj_feat(
    const float* __restrict__ mm, const unsigned short* __restrict__ WS2,
    unsigned short* __restrict__ Fl, unsigned short* __restrict__ Fr) {
  const int tid = threadIdx.x;
  const int lane = tid & 63, w = tid >> 6;
  const int n = lane & 15, q = lane >> 4;
  const int m0 = blockIdx.y * 16;
  const int cg = blockIdx.x * 4 + w;  // 0..63
  const int c0 = cg * 16;

  f32x4 acc = {0.f, 0.f, 0.f, 0.f};
#pragma unroll 4
  for (int kc = 0; kc < 64; ++kc) {
    const float* arow = mm + (size_t)(m0 + n) * 2048 + kc * 32 + q * 8;
    float4 a0 = *(const float4*)(arow);
    float4 a1 = *(const float4*)(arow + 4);
    short8 a;
    a[0] = (short)f2bf(a0.x); a[1] = (short)f2bf(a0.y);
    a[2] = (short)f2bf(a0.z); a[3] = (short)f2bf(a0.w);
    a[4] = (short)f2bf(a1.x); a[5] = (short)f2bf(a1.y);
    a[6] = (short)f2bf(a1.z); a[7] = (short)f2bf(a1.w);
    short8 b = *(const short8*)(WS2 + (size_t)(cg * 64 + kc) * 512 + lane * 8);
    acc = __builtin_amdgcn_mfma_f32_16x16x32_bf16(a, b, acc, 0, 0, 0);
  }
#pragma unroll
  for (int e = 0; e < 4; ++e) {
    int row = m0 + q * 4 + e;
    int col = c0 + n;
    unsigned short v = f2bf(acc[e]);
    if (col < 512) Fl[(size_t)row * 512 + col] = v;
    else           Fr[(size_t)row * 512 + (col - 512)] = v;
  }
}

// ---------------------------------------------------------------------------
// K_prod: materialize pair "products" in MFMA B-fragment order, quad-packed.
// Granule id = (qg*17 + kc)*9 + t ; lane (q,n), elem e: k = kc*32 + q*8 + e.
//   t<8 : group g = qg*4 + (t>>1), col j = (t&1)*16 + n      (full tiles)
//   t=8 : group g = qg*4 + (n>>2), col j = 32 + (n&3)        (shared remainder)
// kc<16 : P = Fl[g,k] * Fr[b*36+j,k]                (feature products)
// kc==16: P = coords[g,a]*coords[b*36+j,bb], ab=q*8+e (<16), else 0
__global__ __launch_bounds__(256) void k_prod(
    const unsigned short* __restrict__ Fl, const unsigned short* __restrict__ Fr,
    const float* __restrict__ coords, unsigned short* __restrict__ Pf) {
  int idx = blockIdx.x * 256 + threadIdx.x;  // 0 .. 2,820,095
  int lane = idx & 63;
  int gran = idx >> 6;          // 0 .. 44063
  int qg = gran / 153;          // 153 = 17 kc * 9 t granules per quad-group
  int rem = gran - qg * 153;
  int kc = rem / 9;
  int t = rem - kc * 9;
  int n = lane & 15, q = lane >> 4;
  int b = qg / 9;
  int g, j;
  if (t < 8) { g = qg * 4 + (t >> 1); j = (t & 1) * 16 + n; }
  else       { g = qg * 4 + (n >> 2); j = 32 + (n & 3); }
  int rowj = b * 36 + j;
  short8 p;
  if (kc < 16) {
    int k0 = kc * 32 + q * 8;
    short8 cl8 = *(const short8*)(Fl + (size_t)g * 512 + k0);
    short8 cr8 = *(const short8*)(Fr + (size_t)rowj * 512 + k0);
#pragma unroll
    for (int e = 0; e < 8; ++e)
      p[e] = (short)f2bf(bf2f((unsigned short)cl8[e]) * bf2f((unsigned short)cr8[e]));
  } else if (q < 2) {
    float4 ci = *(const float4*)(coords + (size_t)g * 4);
    float4 cj = *(const float4*)(coords + (size_t)rowj * 4);
#pragma unroll
    for (int e = 0; e < 8; ++e) {
      int a = q * 2 + (e >> 2);  // 0..3 (q<2)
      float ca = (a == 0) ? ci.x : (a == 1) ? ci.y : (a == 2) ? ci.z : ci.w;
      float cb = ((e & 3) == 0) ? cj.x : ((e & 3) == 1) ? cj.y
               : ((e & 3) == 2) ? cj.z : cj.w;
      p[e] = (short)f2bf(ca * cb);
    }
  } else {
#pragma unroll
    for (int e = 0; e < 8; ++e) p[e] = 0;
  }
  *(short8*)(Pf + (size_t)idx * 8) = p;
}

// ---------------------------------------------------------------------------
// K4: streaming GEMM + max-over-j + residual. NK=17 chunks. UNCHANGED from
// v9/v12 (best measured: 116us, WRITE 9.3MB, VGPR 64).
// 512 thr / 8 waves, r=2, XCD-clustered grid. Counted-vmcnt FIFO ring:
//   ring[3][8*512]: granules t=0..7 staged 2 chunks ahead (1 gl2lds/wave,
//   uniform); g8[17*512]: granule t=8 all chunks, prologue-staged.
//   Body(c): A(c+1) loads; stage(c+2); 8x{ds_read;2 MFMA}+g8 pair;
//   s_waitcnt vmcnt(3); s_barrier.  Manual 3x-unroll, static indices.
__global__ __launch_bounds__(512, 4) void k_pairwise(
    const unsigned short* __restrict__ Pf, const unsigned short* __restrict__ WS,
    const float* __restrict__ mm, float* __restrict__ out) {
  __shared__ __align__(16) unsigned short ring[3][8 * 512];  // 24 KB
  __shared__ __align__(16) unsigned short g8[17 * 512];      // 17 KB

  const int tid = threadIdx.x;
  const int lane = tid & 63, w = tid >> 6;  // w 0..7
  const int n = lane & 15, q = lane >> 4;
  const int bx = blockIdx.x;
  const int x = bx & 7;       // XCD id under round-robin dispatch
  const int m = bx >> 3;      // 0..287 per-XCD slot
  const int dt = m & 7;       // d-tile: siblings consecutive on the XCD
  const int qg = x * 36 + (m >> 3);  // qg clustered per XCD (bijective)
  const int g0 = qg * 4;

  f32x4 acc[9][2];
#pragma unroll
  for (int t = 0; t < 9; ++t)
#pragma unroll
    for (int r = 0; r < 2; ++r) acc[t][r] = (f32x4){0.f, 0.f, 0.f, 0.f};

  // A granule (r, kc): WS + ((dt*16 + w*2 + r)*17 + kc)*512 + lane*8
  const unsigned short* Abase = WS + ((size_t)(dt * 16 + w * 2) * 17) * 512 + lane * 8;
  // B granule (kc, t): Pf + ((qg*17 + kc)*9 + t)*512 + lane*8
  const unsigned short* Bbase = Pf + (size_t)qg * 17 * 9 * 512;

  short8 a00, a01, a10, a11, a20, a21;  // A slots 0,1,2 (rotation static)

  // ---- prologue: ring chunks 0,1 (granule t=w); g8 all 17 chunks; A(0)
  gl2lds16(Bbase + (size_t)w * 512 + lane * 8, &ring[0][w * 512]);
  gl2lds16(Bbase + (size_t)(9 + w) * 512 + lane * 8, &ring[1][w * 512]);
  for (int s = w; s < 17; s += 8)
    gl2lds16(Bbase + (size_t)(s * 9 + 8) * 512 + lane * 8, &g8[s * 512]);
  a00 = *(const short8*)(Abase);
  a01 = *(const short8*)(Abase + 17 * 512);
  __syncthreads();  // one-time full drain

// Body C: uses A slot SU, loads A(C+1) into slot SN, reads ring[RU],
// stages chunk C+2 into ring[RS]; DOSTAGE/VMN per position.
#define KBODY(C, RU, RS, aU0, aU1, aN0, aN1, DOSTAGE, VMN)                   \
  {                                                                          \
    aN0 = *(const short8*)(Abase + (size_t)((C) + 1) * 512);                 \
    aN1 = *(const short8*)(Abase + (size_t)(17 + (C) + 1) * 512);            \
    if (DOSTAGE) {                                                           \
      const unsigned short* bn =                                             \
          Bbase + (size_t)(((C) + 2) * 9) * 512 + lane * 8;                  \
      gl2lds16(bn + (size_t)w * 512, &ring[RS][w * 512]);                    \
    }                                                                        \
    _Pragma("unroll")                                                        \
    for (int t = 0; t < 8; ++t) {                                            \
      short8 bt = *(const short8*)(&ring[RU][t * 512 + lane * 8]);           \
      acc[t][0] = __builtin_amdgcn_mfma_f32_16x16x32_bf16(aU0, bt, acc[t][0], 0, 0, 0); \
      acc[t][1] = __builtin_amdgcn_mfma_f32_16x16x32_bf16(aU1, bt, acc[t][1], 0, 0, 0); \
    }                                                                        \
    {                                                                        \
      short8 b8 = *(const short8*)(&g8[(C) * 512 + lane * 8]);               \
      acc[8][0] = __builtin_amdgcn_mfma_f32_16x16x32_bf16(aU0, b8, acc[8][0], 0, 0, 0); \
      acc[8][1] = __builtin_amdgcn_mfma_f32_16x16x32_bf16(aU1, b8, acc[8][1], 0, 0, 0); \
    }                                                                        \
    asm volatile("s_waitcnt vmcnt(" #VMN ")" ::: "memory");                  \
    __builtin_amdgcn_s_barrier();                                            \
  }

  // main loop: chunks 0..14 (5 x 3 bodies; ring & A-slot rotation static)
  for (int k3 = 0; k3 < 15; k3 += 3) {
    KBODY(k3 + 0, 0, 2, a00, a01, a10, a11, 1, 3);
    KBODY(k3 + 1, 1, 0, a10, a11, a20, a21, 1, 3);
    KBODY(k3 + 2, 2, 1, a20, a21, a00, a01, 1, 3);
  }
  // chunk 15: slot0 in use, loads A(16)->slot1, no stage; vmcnt(2) drains
  // stage(16) (issued at body 14).
  KBODY(15, 0, 2, a00, a01, a10, a11, 0, 2);
  // chunk 16: final, no loads/stage/barrier
  {
#pragma unroll
    for (int t = 0; t < 8; ++t) {
      short8 bt = *(const short8*)(&ring[1][t * 512 + lane * 8]);
      acc[t][0] = __builtin_amdgcn_mfma_f32_16x16x32_bf16(a10, bt, acc[t][0], 0, 0, 0);
      acc[t][1] = __builtin_amdgcn_mfma_f32_16x16x32_bf16(a11, bt, acc[t][1], 0, 0, 0);
    }
    {
      short8 b8 = *(const short8*)(&g8[16 * 512 + lane * 8]);
      acc[8][0] = __builtin_amdgcn_mfma_f32_16x16x32_bf16(a10, b8, acc[8][0], 0, 0, 0);
      acc[8][1] = __builtin_amdgcn_mfma_f32_16x16x32_bf16(a11, b8, acc[8][1], 0, 0, 0);
    }
  }
#undef KBODY

  // epilogue: per (ii,r,e): max over full tiles 2ii,2ii+1 (j=n, 16+n) and the
  // shared tile's lanes with n>>2==ii (j=32+(n&3)); xor-reduce over 16 n-lanes.
#pragma unroll
  for (int r = 0; r < 2; ++r) {
#pragma unroll
    for (int e = 0; e < 4; ++e) {
      float vs = acc[8][r][e];
#pragma unroll
      for (int ii = 0; ii < 4; ++ii) {
        float v = fmaxf(acc[ii * 2][r][e], acc[ii * 2 + 1][r][e]);
        v = fmaxf(v, ((n >> 2) == ii) ? vs : -1e30f);
#pragma unroll
        for (int s = 1; s < 16; s <<= 1) v = fmaxf(v, __shfl_xor(v, s, 64));
        if (n == 0) {
          int d = dt * 256 + w * 32 + r * 16 + q * 4 + e;
          size_t o = (size_t)(g0 + ii) * 2048 + d;
          out[o] = v + mm[o];
        }
      }
    }
  }
}

// ---------------------------------------------------------------------------
extern "C" void kernel_launch(void* const* d_in, const int* in_sizes, int n_in,
                              void* d_out, int out_size, void* d_ws, size_t ws_size,
                              hipStream_t stream) {
  const float* mm     = (const float*)d_in[0];
  const float* coords = (const float*)d_in[1];
  const float* Wcl    = (const float*)d_in[2];
  const float* Wcr    = (const float*)d_in[3];
  const float* Wcout  = (const float*)d_in[4];
  const float* Wfl    = (const float*)d_in[5];
  const float* Wfr    = (const float*)d_in[6];
  const float* Wfout  = (const float*)d_in[7];
  float* out = (float*)d_out;

  // workspace ~54 MB (mmb deleted)
  unsigned short* Fl  = (unsigned short*)d_ws;              // [1152][512] bf16
  unsigned short* Fr  = Fl + (size_t)1152 * 512;            // [1152][512] bf16
  unsigned short* WS  = Fr + (size_t)1152 * 512;            // 139264 gran x 8
  unsigned short* WS2 = WS + (size_t)139264 * 8;            // 262144 gran x 8
  unsigned short* Pf  = WS2 + (size_t)262144 * 8;           // 44064 gran x 512 (45MB)

  k_mc<<<128, 256, 0, stream>>>(Wcl, Wcr, Wcout, WS);
  k_prep<<<1568, 256, 0, stream>>>(Wfout, Wfl, Wfr, WS, WS2);
  k_proj_feat<<<dim3(16, 72), 256, 0, stream>>>(mm, WS2, Fl, Fr);
  k_prod<<<11016, 256, 0, stream>>>(Fl, Fr, coords, Pf);
  k_pairwise<<<2304, 512, 0, stream>>>(Pf, WS, mm, out);
}